// Round 1
// 566.319 us; speedup vs baseline: 1.1294x; 1.1294x over previous
//
#include <hip/hip_runtime.h>
#include <math.h>

#define DIM   768
#define LAT   20
#define NP    10
#define NB    16
#define SEQ   4096
#define SEQX  (NP + 1 + SEQ)        // 4107
#define NXROWS (NB * SEQX)          // 65712
#define NLROWS (NB * SEQ)           // 65536
#define NROWS  (NXROWS + NLROWS)    // 131248
#define EPSF  1e-5f

typedef __attribute__((ext_vector_type(8))) short  v8s;
typedef __attribute__((ext_vector_type(4))) float  v4f;
typedef __attribute__((ext_vector_type(4))) unsigned short u16x4;
typedef __attribute__((ext_vector_type(8))) unsigned short u16x8;

__device__ __forceinline__ float sigmoidf_(float z) { return 1.f / (1.f + __expf(-z)); }

__device__ __forceinline__ unsigned short bf16u(float v) {
    unsigned u = __builtin_bit_cast(unsigned, v);
    unsigned r = u + 0x7fffu + ((u >> 16) & 1u);   // RNE
    return (unsigned short)(r >> 16);
}

// async 16B/lane global->LDS: LDS dest is wave-uniform base + lane*16 (HW rule)
__device__ __forceinline__ void gload_lds16(const void* g, void* s) {
    __builtin_amdgcn_global_load_lds(
        (const __attribute__((address_space(1))) unsigned int*)g,
        (__attribute__((address_space(3))) unsigned int*)s, 16, 0, 0);
}

// ---------------------------------------------------------------------------
// K0: build the bf16 W-fragment image (exact LDS layout k_down consumes) once.
// slot = (fs*2+nt)*64 + lane ; 8 ushorts per slot.  3072 slots = 48 KB.
// B-frag layout (16x16x32): B[k = (l>>4)*8+e][n = nt*16 + (l&15)], zeros n>=LAT.
// ---------------------------------------------------------------------------
__global__ __launch_bounds__(256) void k_wfrag(const float* __restrict__ Wd,
                                               unsigned short* __restrict__ wf)
{
    int slot = blockIdx.x * 256 + threadIdx.x;     // 0..3071
    int fs = slot >> 7, rem = slot & 127;
    int nt = rem >> 6, l = rem & 63;
    int n = nt * 16 + (l & 15);
    int q = l >> 4;
    u16x8 w;
#pragma unroll
    for (int e = 0; e < 8; e++) {
        int k = fs * 32 + q * 8 + e;
        float v = (n < LAT) ? Wd[k * LAT + n] : 0.f;
        w[e] = bf16u(v);
    }
    *(u16x8*)&wf[slot * 8] = w;
}

// ---------------------------------------------------------------------------
// K1a v2: down-projection, latency-hiding rewrite.
// Per wave: one 16-row m-tile, 24 K-steps (K=32 each).  A-fragments are 8
// contiguous k's per lane -> fetched DIRECTLY from global via global_load_lds
// into a wave-private 4-slot LDS ring (2 KB/slot), consumed with counted
// vmcnt(6) -- no barriers in the K-loop.  W-fragments: 48 KB LDS, copied
// linearly from the prebuilt image.  LDS total 81920 B -> 2 blocks/CU; in
// flight: 8 waves x 8 x 1KB = 64 KB/CU >> latency-BW product (~9 KB).
// ---------------------------------------------------------------------------
#define WF_B    49152      // W-frag bytes (24 fs * 2 nt * 64 lanes * 16 B)
#define SLOT_B  2048       // 16 rows * 32 k * 4 B
#define RING_B  (4 * SLOT_B)

__global__ __launch_bounds__(256, 2) void k_down(const float* __restrict__ x,
                                                 const float* __restrict__ loc,
                                                 const unsigned short* __restrict__ wf,
                                                 const float* __restrict__ bd,
                                                 float* __restrict__ lat)
{
    __shared__ __align__(16) unsigned short lds[(WF_B + 4 * RING_B) / 2]; // 81920 B
    const int tid = threadIdx.x, l = tid & 63, w = tid >> 6;

    // ---- W-frag fill: linear 48 KB copy, 12 x (256 lanes x 16 B) ----
    {
        const char* g = (const char*)wf;
        char* s = (char*)lds;
#pragma unroll
        for (int i = 0; i < 12; ++i) {
            int off = i * 4096 + w * 1024;
            gload_lds16(g + off + l * 16, s + off);
        }
    }
    asm volatile("s_waitcnt vmcnt(0)" ::: "memory");
    __syncthreads();                       // the ONLY barrier

    const int r0 = blockIdx.x * 64 + w * 16;   // 16-row group per wave
    if (r0 >= NROWS) return;                   // no barriers after this: safe
    // NXROWS and NROWS are multiples of 16 -> src choice is wave-uniform
    const float* srcb = (r0 < NXROWS) ? x + (size_t)r0 * DIM
                                      : loc + (size_t)(r0 - NXROWS) * DIM;
    // lane (m = l&15, q = l>>4) fetches row m, k-bytes [q*32 .. q*32+15] (+16)
    const float* gp = srcb + (size_t)(l & 15) * DIM + (l >> 4) * 8;
    char* ring = (char*)lds + WF_B + w * RING_B;

    // prologue: prefetch steps 0..3
#pragma unroll
    for (int p = 0; p < 4; ++p) {
        gload_lds16(gp + p * 32,     ring + p * SLOT_B);
        gload_lds16(gp + p * 32 + 4, ring + p * SLOT_B + 1024);
    }

    v4f acc0 = {0.f, 0.f, 0.f, 0.f}, acc1 = {0.f, 0.f, 0.f, 0.f};

#define CVT8(A, F0, F1)                                                   \
    A[0] = (short)bf16u(F0.x); A[1] = (short)bf16u(F0.y);                 \
    A[2] = (short)bf16u(F0.z); A[3] = (short)bf16u(F0.w);                 \
    A[4] = (short)bf16u(F1.x); A[5] = (short)bf16u(F1.y);                 \
    A[6] = (short)bf16u(F1.z); A[7] = (short)bf16u(F1.w);

#define KSTEP(T, VMSTR) do {                                              \
    asm volatile("s_waitcnt " VMSTR ::: "memory");                        \
    float4 f0 = *(const float4*)(ring + ((T) & 3) * SLOT_B + l * 16);     \
    float4 f1 = *(const float4*)(ring + ((T) & 3) * SLOT_B + 1024 + l * 16); \
    v8s a; CVT8(a, f0, f1);                                               \
    v8s b0 = *(const v8s*)&lds[(((T) * 2 + 0) * 64 + l) * 8];             \
    v8s b1 = *(const v8s*)&lds[(((T) * 2 + 1) * 64 + l) * 8];             \
    acc0 = __builtin_amdgcn_mfma_f32_16x16x32_bf16(a, b0, acc0, 0, 0, 0); \
    acc1 = __builtin_amdgcn_mfma_f32_16x16x32_bf16(a, b1, acc1, 0, 0, 0); \
    if ((T) + 4 < 24) {                                                   \
        asm volatile("s_waitcnt lgkmcnt(0)" ::: "memory");                \
        gload_lds16(gp + ((T) + 4) * 32,     ring + ((T) & 3) * SLOT_B);  \
        gload_lds16(gp + ((T) + 4) * 32 + 4, ring + ((T) & 3) * SLOT_B + 1024); \
    }                                                                     \
} while (0)

    KSTEP(0,  "vmcnt(6)");  KSTEP(1,  "vmcnt(6)");  KSTEP(2,  "vmcnt(6)");
    KSTEP(3,  "vmcnt(6)");  KSTEP(4,  "vmcnt(6)");  KSTEP(5,  "vmcnt(6)");
    KSTEP(6,  "vmcnt(6)");  KSTEP(7,  "vmcnt(6)");  KSTEP(8,  "vmcnt(6)");
    KSTEP(9,  "vmcnt(6)");  KSTEP(10, "vmcnt(6)");  KSTEP(11, "vmcnt(6)");
    KSTEP(12, "vmcnt(6)");  KSTEP(13, "vmcnt(6)");  KSTEP(14, "vmcnt(6)");
    KSTEP(15, "vmcnt(6)");  KSTEP(16, "vmcnt(6)");  KSTEP(17, "vmcnt(6)");
    KSTEP(18, "vmcnt(6)");  KSTEP(19, "vmcnt(6)");  KSTEP(20, "vmcnt(6)");
    KSTEP(21, "vmcnt(4)");  KSTEP(22, "vmcnt(2)");  KSTEP(23, "vmcnt(0)");
#undef KSTEP
#undef CVT8

    // ---- epilogue: bias + quick_gelu, scattered store (identical numerics) ----
    int col = l & 15, half = l >> 4;
#pragma unroll
    for (int nt = 0; nt < 2; nt++) {
        int j = nt * 16 + col;
        if (j >= LAT) continue;
        float bdj = bd[j];
        v4f A = nt ? acc1 : acc0;
#pragma unroll
        for (int r = 0; r < 4; r++) {
            int rowg = r0 + half * 4 + r;          // r0+15 < NROWS guaranteed
            float z = A[r] + bdj;
            lat[(size_t)rowg * LAT + j] = z * sigmoidf_(1.702f * z);
        }
    }
}

// ---------------------------------------------------------------------------
// K1b: up-projection for cls + global_img rows (unchanged).
// ---------------------------------------------------------------------------
__global__ __launch_bounds__(192, 3) void k_up(const float* __restrict__ lat,
                                               const float* __restrict__ Wu,
                                               const float* __restrict__ bu,
                                               float* __restrict__ out)
{
    int t = threadIdx.x;
    float4 wu[LAT];
#pragma unroll
    for (int k = 0; k < LAT; k++) wu[k] = ((const float4*)Wu)[k * 192 + t];
    float4 bv = ((const float4*)bu)[t];

    __shared__ float latile[64 * LAT];
    int rowbase = blockIdx.x * 64;
    {   // coalesced tile load: 320 float4 (reads past lat_x end land in lat_l, harmless)
        const float4* src = (const float4*)(lat + (size_t)rowbase * LAT);
        for (int idx = t; idx < 320; idx += 192) ((float4*)latile)[idx] = src[idx];
    }
    __syncthreads();

    int idx0 = rowbase % SEQX;
    for (int i = 0; i < 64; i++) {
        int row = rowbase + i;
        if (row >= NXROWS) break;
        int idx = idx0 + i;
        if (idx >= SEQX) idx -= SEQX;
        if (idx < NP) continue;            // prompt rows written by k_prompt_out
        const float* lp = latile + i * LAT;
        float4 acc = bv;
#pragma unroll
        for (int k = 0; k < LAT; k++) {
            float v = lp[k];
            acc.x += v * wu[k].x; acc.y += v * wu[k].y;
            acc.z += v * wu[k].z; acc.w += v * wu[k].w;
        }
        ((float4*)out)[(size_t)row * 192 + t] = acc;
    }
}

// ---------------------------------------------------------------------------
// K2: per-batch tiny math (unchanged)
// ---------------------------------------------------------------------------
__global__ __launch_bounds__(64) void k_small(const float* __restrict__ lat_x,
    const float* __restrict__ Wgq, const float* __restrict__ bgq,
    const float* __restrict__ Wlq, const float* __restrict__ blq,
    const float* __restrict__ lncg, const float* __restrict__ lncb,
    const float* __restrict__ Wc1, const float* __restrict__ bc1,
    const float* __restrict__ Wc2, const float* __restrict__ bc2,
    const float* __restrict__ lngg, const float* __restrict__ lngb,
    const float* __restrict__ Wg, const float* __restrict__ bg,
    float* __restrict__ qg, float* __restrict__ ql,
    float* __restrict__ imp, float* __restrict__ gw)
{
    int b = blockIdx.x, t = threadIdx.x;
    __shared__ float cls[LAT], clsln[LAT], h1[64];
    __shared__ float mu_s, rs_s;

    const float* cp = lat_x + (size_t)(b * SEQX + NP) * LAT;
    if (t < LAT) cls[t] = cp[t];
    __syncthreads();

    if (t == 0) {
        float m = 0.f;
        for (int k = 0; k < LAT; k++) m += cls[k];
        m /= LAT;
        float v = 0.f;
        for (int k = 0; k < LAT; k++) { float d = cls[k] - m; v += d * d; }
        v /= LAT;
        float rs = rsqrtf(v + EPSF);
        mu_s = m; rs_s = rs;
        float s = bg[0];
        for (int k = 0; k < LAT; k++)
            s += ((cls[k] - m) * rs * lngg[k] + lngb[k]) * Wg[k];
        gw[b] = sigmoidf_(s);
    }
    __syncthreads();
    if (t < LAT) clsln[t] = (cls[t] - mu_s) * rs_s * lncg[t] + lncb[t];
    __syncthreads();

    {
        float s = bc1[t];
        for (int k = 0; k < LAT; k++) s += clsln[k] * Wc1[k * 64 + t];
        h1[t] = 0.5f * s * (1.f + erff(s * 0.70710678118f));
    }
    __syncthreads();
    if (t < NP) {
        float s = bc2[t];
        for (int i = 0; i < 64; i++) s += h1[i] * Wc2[i * NP + t];
        imp[b * NP + t] = sigmoidf_(s);
    }
    for (int idx = t; idx < NP * LAT; idx += 64) {
        int p = idx / LAT, j = idx % LAT;
        const float* pl = lat_x + (size_t)(b * SEQX + p) * LAT;
        float sg = bgq[j], sl = blq[j];
        for (int k = 0; k < LAT; k++) {
            float v = pl[k];
            sg += v * Wgq[k * LAT + j];
            sl += v * Wlq[k * LAT + j];
        }
        qg[(b * NP + p) * LAT + j] = sg;
        ql[(b * NP + p) * LAT + j] = sl;
    }
}

// ---------------------------------------------------------------------------
// K3: attention context (unchanged)
// ---------------------------------------------------------------------------
__global__ __launch_bounds__(256) void k_attn(const float* __restrict__ lat_x,
                                              const float* __restrict__ lat_l,
                                              const float* __restrict__ qg,
                                              const float* __restrict__ ql,
                                              float* __restrict__ ctxg,
                                              float* __restrict__ ctxl)
{
    int b = blockIdx.x, p = blockIdx.y, ty = blockIdx.z;
    const float* tok = (ty == 0) ? lat_x + (size_t)(b * SEQX + NP + 1) * LAT
                                 : lat_l + (size_t)b * SEQ * LAT;
    const float* q = ((ty == 0) ? qg : ql) + (size_t)(b * NP + p) * LAT;
    float* ctx = ((ty == 0) ? ctxg : ctxl) + (size_t)(b * NP + p) * LAT;

    int t = threadIdx.x;
    __shared__ float qs[LAT];
    __shared__ float red[128];
    __shared__ float Ms;
    __shared__ float tot[21];
    if (t < LAT) qs[t] = q[t];
    __syncthreads();

    const float scale = 0.22360679775f;   // 1/sqrt(20)
    float lg[16];
    float lmax = -1e30f;
    for (int i = 0; i < 16; i++) {
        const float* tk = tok + (size_t)(t + 256 * i) * LAT;
        float s = 0.f;
#pragma unroll
        for (int k = 0; k < LAT; k++) s += qs[k] * tk[k];
        s *= scale;
        lg[i] = s;
        lmax = fmaxf(lmax, s);
    }
    int wave = t >> 6, lane = t & 63;
    for (int off = 32; off; off >>= 1) lmax = fmaxf(lmax, __shfl_down(lmax, off, 64));
    if (lane == 0) red[wave] = lmax;
    __syncthreads();
    if (t == 0) Ms = fmaxf(fmaxf(red[0], red[1]), fmaxf(red[2], red[3]));
    __syncthreads();
    float M = Ms;

    float vals[21];
#pragma unroll
    for (int j = 0; j < 21; j++) vals[j] = 0.f;
    for (int i = 0; i < 16; i++) {
        float w = __expf(lg[i] - M);
        vals[20] += w;
        const float* tk = tok + (size_t)(t + 256 * i) * LAT;
#pragma unroll
        for (int k = 0; k < LAT; k++) vals[k] += w * tk[k];
    }
#pragma unroll
    for (int j = 0; j < 21; j++) {
        float v = vals[j];
        for (int off = 32; off; off >>= 1) v += __shfl_down(v, off, 64);
        vals[j] = v;
    }
    __syncthreads();
    if (lane == 0)
        for (int j = 0; j < 21; j++) red[wave * 21 + j] = vals[j];
    __syncthreads();
    if (t < 21) tot[t] = red[t] + red[21 + t] + red[42 + t] + red[63 + t];
    __syncthreads();
    if (t < LAT) ctx[t] = tot[t] / tot[20];
}

// ---------------------------------------------------------------------------
// K4: prompt-row outputs (unchanged)
// ---------------------------------------------------------------------------
__global__ __launch_bounds__(192) void k_prompt_out(const float* __restrict__ ctxg,
                                                    const float* __restrict__ ctxl,
                                                    const float* __restrict__ imp,
                                                    const float* __restrict__ gw,
                                                    const float* __restrict__ Wu,
                                                    const float* __restrict__ bu,
                                                    float* __restrict__ out)
{
    int b = blockIdx.x, p = blockIdx.y, t = threadIdx.x;
    __shared__ float enh[LAT];
    if (t < LAT) {
        float g = gw[b];
        size_t o = (size_t)(b * NP + p) * LAT + t;
        float e = g * ctxg[o] + (1.f - g) * ctxl[o];
        enh[t] = e * imp[b * NP + p];
    }
    __syncthreads();
    float4 acc = ((const float4*)bu)[t];
#pragma unroll
    for (int k = 0; k < LAT; k++) {
        float4 w = ((const float4*)Wu)[k * 192 + t];
        float e = enh[k];
        acc.x += e * w.x; acc.y += e * w.y; acc.z += e * w.z; acc.w += e * w.w;
    }
    ((float4*)out)[(size_t)(b * SEQX + p) * 192 + t] = acc;
}

// ---------------------------------------------------------------------------
extern "C" void kernel_launch(void* const* d_in, const int* in_sizes, int n_in,
                              void* d_out, int out_size, void* d_ws, size_t ws_size,
                              hipStream_t stream)
{
    const float* x    = (const float*)d_in[0];
    const float* loc  = (const float*)d_in[1];
    const float* Wd   = (const float*)d_in[2];
    const float* bd   = (const float*)d_in[3];
    const float* Wu   = (const float*)d_in[4];
    const float* bu   = (const float*)d_in[5];
    const float* Wgq  = (const float*)d_in[6];
    const float* bgq  = (const float*)d_in[7];
    const float* Wlq  = (const float*)d_in[8];
    const float* blq  = (const float*)d_in[9];
    const float* lncg = (const float*)d_in[10];
    const float* lncb = (const float*)d_in[11];
    const float* Wc1  = (const float*)d_in[12];
    const float* bc1  = (const float*)d_in[13];
    const float* Wc2  = (const float*)d_in[14];
    const float* bc2  = (const float*)d_in[15];
    const float* lngg = (const float*)d_in[16];
    const float* lngb = (const float*)d_in[17];
    const float* Wg   = (const float*)d_in[18];
    const float* bg   = (const float*)d_in[19];
    float* out = (float*)d_out;

    float* ws   = (float*)d_ws;
    float* lat_x = ws;                                   // NXROWS*LAT
    float* lat_l = lat_x + (size_t)NXROWS * LAT;         // NLROWS*LAT (contiguous)
    float* qg    = lat_l + (size_t)NLROWS * LAT;
    float* ql    = qg + NB * NP * LAT;
    float* ctxg  = ql + NB * NP * LAT;
    float* ctxl  = ctxg + NB * NP * LAT;
    float* impw  = ctxl + NB * NP * LAT;
    float* gww   = impw + NB * NP;
    unsigned short* wfrag = (unsigned short*)(gww + NB); // 48 KB frag image (16B-aligned)

    k_wfrag<<<12, 256, 0, stream>>>(Wd, wfrag);
    k_down<<<(NROWS + 63) / 64, 256, 0, stream>>>(x, loc, wfrag, bd, lat_x);
    k_up<<<(NXROWS + 63) / 64, 192, 0, stream>>>(lat_x, Wu, bu, out);
    k_small<<<NB, 64, 0, stream>>>(lat_x, Wgq, bgq, Wlq, blq, lncg, lncb,
                                   Wc1, bc1, Wc2, bc2, lngg, lngb, Wg, bg,
                                   qg, ql, impw, gww);
    k_attn<<<dim3(NB, NP, 2), 256, 0, stream>>>(lat_x, lat_l, qg, ql, ctxg, ctxl);
    k_prompt_out<<<dim3(NB, NP), 192, 0, stream>>>(ctxg, ctxl, impw, gww, Wu, bu, out);
}

// Round 2
// 558.519 us; speedup vs baseline: 1.1452x; 1.0140x over previous
//
#include <hip/hip_runtime.h>
#include <math.h>

#define DIM   768
#define LAT   20
#define NP    10
#define NB    16
#define SEQ   4096
#define SEQX  (NP + 1 + SEQ)        // 4107
#define NXROWS (NB * SEQX)          // 65712
#define NLROWS (NB * SEQ)           // 65536
#define NROWS  (NXROWS + NLROWS)    // 131248 (multiple of 16)
#define EPSF  1e-5f

typedef __attribute__((ext_vector_type(8))) short  v8s;
typedef __attribute__((ext_vector_type(4))) float  v4f;
typedef __attribute__((ext_vector_type(4))) unsigned int u32x4;
typedef __attribute__((ext_vector_type(8))) unsigned short u16x8;

__device__ __forceinline__ float sigmoidf_(float z) { return 1.f / (1.f + __expf(-z)); }

__device__ __forceinline__ unsigned short bf16u(float v) {
    unsigned u = __builtin_bit_cast(unsigned, v);
    unsigned r = u + 0x7fffu + ((u >> 16) & 1u);   // RNE
    return (unsigned short)(r >> 16);
}

// packed f32->bf16 RNE (same rounding as bf16u for all normal/zero inputs)
__device__ __forceinline__ unsigned cvtpk(float lo, float hi) {
    unsigned r;
    asm("v_cvt_pk_bf16_f32 %0, %1, %2" : "=v"(r) : "v"(lo), "v"(hi));
    return r;
}

// async 16B/lane global->LDS: LDS dest is wave-uniform base + lane*16 (HW rule)
__device__ __forceinline__ void gload_lds16(const void* g, void* s) {
    __builtin_amdgcn_global_load_lds(
        (const __attribute__((address_space(1))) unsigned int*)g,
        (__attribute__((address_space(3))) unsigned int*)s, 16, 0, 0);
}

// ---------------------------------------------------------------------------
// K0: build the bf16 W-fragment image (exact LDS layout k_down consumes) once.
// slot = (fs*2+nt)*64 + lane ; 8 ushorts per slot.  3072 slots = 48 KB.
// B-frag layout (16x16x32): B[k = (l>>4)*8+e][n = nt*16 + (l&15)], zeros n>=LAT.
// ---------------------------------------------------------------------------
__global__ __launch_bounds__(256) void k_wfrag(const float* __restrict__ Wd,
                                               unsigned short* __restrict__ wf)
{
    int slot = blockIdx.x * 256 + threadIdx.x;     // 0..3071
    int fs = slot >> 7, rem = slot & 127;
    int nt = rem >> 6, l = rem & 63;
    int n = nt * 16 + (l & 15);
    int q = l >> 4;
    u16x8 w;
#pragma unroll
    for (int e = 0; e < 8; e++) {
        int k = fs * 32 + q * 8 + e;
        float v = (n < LAT) ? Wd[k * LAT + n] : 0.f;
        w[e] = bf16u(v);
    }
    *(u16x8*)&wf[slot * 8] = w;
}

// ---------------------------------------------------------------------------
// K1a v3: down-projection, line-contiguous staging.
// Per wave: 16 rows.  K split into 12 chunks of 64 k (= 256 B/row).  Each
// chunk staged by 4 global_load_lds: lanes cover 4 rows x 256 B CONTIGUOUS
// (8 fully-covered 128-B lines per instruction — copy-benchmark pattern).
// LDS slot layout: [16 rows][16 chunks of 16 B], with chunk index XOR-swizzled
// by (row&7) on BOTH the global source (coalescing preserved: same address
// set, lanes permuted) and the fragment ds_read (8 lanes / 4-bank group =
// conflict-free).  2-slot ring per wave, counted vmcnt(4), zero K-loop
// barriers.  LDS: 48 KB wfrag + 4 waves * 8 KB = 80 KB -> 2 blocks/CU.
// ---------------------------------------------------------------------------
#define WF_B    49152      // W-frag bytes (24 fs * 2 nt * 64 lanes * 16 B)
#define RING0   WF_B

__global__ __launch_bounds__(256, 2) void k_down(const float* __restrict__ x,
                                                 const float* __restrict__ loc,
                                                 const unsigned short* __restrict__ wf,
                                                 const float* __restrict__ bd,
                                                 float* __restrict__ lat)
{
    __shared__ __align__(16) unsigned short lds[(WF_B + 4 * 8192) / 2]; // 81920 B
    const int tid = threadIdx.x, l = tid & 63, w = tid >> 6;

    // ---- W-frag fill: linear 48 KB copy, 12 x (256 lanes x 16 B) ----
    {
        const char* g = (const char*)wf;
        char* s = (char*)lds;
#pragma unroll
        for (int i = 0; i < 12; ++i) {
            int off = i * 4096 + w * 1024;
            gload_lds16(g + off + l * 16, s + off);
        }
    }
    asm volatile("s_waitcnt vmcnt(0)" ::: "memory");
    __syncthreads();                       // the ONLY barrier

    const int r0 = blockIdx.x * 64 + w * 16;   // 16-row group per wave
    if (r0 >= NROWS) return;                   // after barrier: safe
    // NXROWS and NROWS are multiples of 16 -> src choice is wave-uniform
    const float* srcb = (r0 < NXROWS) ? x + (size_t)r0 * DIM
                                      : loc + (size_t)(r0 - NXROWS) * DIM;

    // ---- per-lane staging pointers: instruction i covers rows 4i..4i+3 ----
    // lane l: row rr = 4i + (l>>4), 16-B chunk cc = l&15, source chunk
    // pre-swizzled by rr&7 so LDS-linear dest == swizzled layout (rule #21).
    const int rrq = l >> 4, cc = l & 15;
    const float* Pp[4];
#pragma unroll
    for (int i = 0; i < 4; ++i) {
        int rr = i * 4 + rrq;
        Pp[i] = srcb + (size_t)rr * DIM + ((cc ^ (rr & 7)) * 4);
    }

    // ---- fragment read addresses (bytes into lds), all-constant indexed ----
    // step fs: s=fs&1, slot=(fs>>1)&1; lane reads row rr=l&15, float k-range
    // [s*32+q*8, +8): global chunks g0=s*8+2q, g1=g0+1; phys = g ^ (rr&7).
    unsigned Aadr[2][2][2];
    {
        int rr = l & 15, q = l >> 4;
#pragma unroll
        for (int sl = 0; sl < 2; ++sl)
#pragma unroll
            for (int s = 0; s < 2; ++s)
#pragma unroll
                for (int h = 0; h < 2; ++h)
                    Aadr[sl][s][h] = RING0 + w * 8192 + sl * 4096 + rr * 256
                                   + (((s * 8 + 2 * q + h) ^ (rr & 7)) << 4);
    }
    const v8s* Bfr = (const v8s*)lds;

    v4f acc0 = {0.f, 0.f, 0.f, 0.f}, acc1 = {0.f, 0.f, 0.f, 0.f};

#define STAGE(C, SL) do {                                                    \
    asm volatile("s_waitcnt lgkmcnt(0)" ::: "memory");  /* slot reads done */\
    char* sb_ = (char*)lds + RING0 + w * 8192 + (SL) * 4096;                 \
    gload_lds16(Pp[0] + (C) * 64, sb_);                                      \
    gload_lds16(Pp[1] + (C) * 64, sb_ + 1024);                               \
    gload_lds16(Pp[2] + (C) * 64, sb_ + 2048);                               \
    gload_lds16(Pp[3] + (C) * 64, sb_ + 3072);                               \
} while (0)

#define KSTEP(FS) do {                                                       \
    float4 f0 = *(const float4*)((const char*)lds +                          \
                                 Aadr[((FS) >> 1) & 1][(FS) & 1][0]);        \
    float4 f1 = *(const float4*)((const char*)lds +                          \
                                 Aadr[((FS) >> 1) & 1][(FS) & 1][1]);        \
    u32x4 u_;                                                                \
    u_[0] = cvtpk(f0.x, f0.y); u_[1] = cvtpk(f0.z, f0.w);                    \
    u_[2] = cvtpk(f1.x, f1.y); u_[3] = cvtpk(f1.z, f1.w);                    \
    v8s a_ = __builtin_bit_cast(v8s, u_);                                    \
    v8s b0 = Bfr[((FS) * 2 + 0) * 64 + l];                                   \
    v8s b1 = Bfr[((FS) * 2 + 1) * 64 + l];                                   \
    acc0 = __builtin_amdgcn_mfma_f32_16x16x32_bf16(a_, b0, acc0, 0, 0, 0);   \
    acc1 = __builtin_amdgcn_mfma_f32_16x16x32_bf16(a_, b1, acc1, 0, 0, 0);   \
} while (0)

#define CHUNK(C, WAITSTR) do {                                               \
    asm volatile("s_waitcnt " WAITSTR ::: "memory");                         \
    KSTEP(2 * (C)); KSTEP(2 * (C) + 1);                                      \
    if ((C) < 10) STAGE((C) + 2, (C) & 1);                                   \
} while (0)

    STAGE(0, 0); STAGE(1, 1);              // prologue: 8 loads in flight

    CHUNK(0,  "vmcnt(4)");  CHUNK(1,  "vmcnt(4)");  CHUNK(2,  "vmcnt(4)");
    CHUNK(3,  "vmcnt(4)");  CHUNK(4,  "vmcnt(4)");  CHUNK(5,  "vmcnt(4)");
    CHUNK(6,  "vmcnt(4)");  CHUNK(7,  "vmcnt(4)");  CHUNK(8,  "vmcnt(4)");
    CHUNK(9,  "vmcnt(4)");  CHUNK(10, "vmcnt(4)");  CHUNK(11, "vmcnt(0)");
#undef CHUNK
#undef KSTEP
#undef STAGE

    // ---- epilogue: bias + quick_gelu, scattered store (identical numerics) ----
    int col = l & 15, half = l >> 4;
#pragma unroll
    for (int nt = 0; nt < 2; nt++) {
        int j = nt * 16 + col;
        if (j >= LAT) continue;
        float bdj = bd[j];
        v4f A = nt ? acc1 : acc0;
#pragma unroll
        for (int r = 0; r < 4; r++) {
            int rowg = r0 + half * 4 + r;          // r0+15 < NROWS guaranteed
            float z = A[r] + bdj;
            lat[(size_t)rowg * LAT + j] = z * sigmoidf_(1.702f * z);
        }
    }
}

// ---------------------------------------------------------------------------
// K1b: up-projection for cls + global_img rows.  (float4 LDS reads; same
// FMA order as before -> bit-identical.)
// ---------------------------------------------------------------------------
__global__ __launch_bounds__(192, 3) void k_up(const float* __restrict__ lat,
                                               const float* __restrict__ Wu,
                                               const float* __restrict__ bu,
                                               float* __restrict__ out)
{
    int t = threadIdx.x;
    float4 wu[LAT];
#pragma unroll
    for (int k = 0; k < LAT; k++) wu[k] = ((const float4*)Wu)[k * 192 + t];
    float4 bv = ((const float4*)bu)[t];

    __shared__ __align__(16) float latile[64 * LAT];
    int rowbase = blockIdx.x * 64;
    {   // coalesced tile load: 320 float4 (reads past lat_x end land in lat_l, harmless)
        const float4* src = (const float4*)(lat + (size_t)rowbase * LAT);
        for (int idx = t; idx < 320; idx += 192) ((float4*)latile)[idx] = src[idx];
    }
    __syncthreads();

    int idx0 = rowbase % SEQX;
    for (int i = 0; i < 64; i++) {
        int row = rowbase + i;
        if (row >= NXROWS) break;
        int idx = idx0 + i;
        if (idx >= SEQX) idx -= SEQX;
        if (idx < NP) continue;            // prompt rows written by k_prompt_out
        const float4* lp4 = (const float4*)(latile + i * LAT);
        float lv[LAT];
        {
            float4 t0 = lp4[0], t1 = lp4[1], t2 = lp4[2], t3 = lp4[3], t4 = lp4[4];
            lv[0]=t0.x; lv[1]=t0.y; lv[2]=t0.z; lv[3]=t0.w;
            lv[4]=t1.x; lv[5]=t1.y; lv[6]=t1.z; lv[7]=t1.w;
            lv[8]=t2.x; lv[9]=t2.y; lv[10]=t2.z; lv[11]=t2.w;
            lv[12]=t3.x; lv[13]=t3.y; lv[14]=t3.z; lv[15]=t3.w;
            lv[16]=t4.x; lv[17]=t4.y; lv[18]=t4.z; lv[19]=t4.w;
        }
        float4 acc = bv;
#pragma unroll
        for (int k = 0; k < LAT; k++) {
            float v = lv[k];
            acc.x += v * wu[k].x; acc.y += v * wu[k].y;
            acc.z += v * wu[k].z; acc.w += v * wu[k].w;
        }
        ((float4*)out)[(size_t)row * 192 + t] = acc;
    }
}

// ---------------------------------------------------------------------------
// K2: per-batch tiny math (unchanged)
// ---------------------------------------------------------------------------
__global__ __launch_bounds__(64) void k_small(const float* __restrict__ lat_x,
    const float* __restrict__ Wgq, const float* __restrict__ bgq,
    const float* __restrict__ Wlq, const float* __restrict__ blq,
    const float* __restrict__ lncg, const float* __restrict__ lncb,
    const float* __restrict__ Wc1, const float* __restrict__ bc1,
    const float* __restrict__ Wc2, const float* __restrict__ bc2,
    const float* __restrict__ lngg, const float* __restrict__ lngb,
    const float* __restrict__ Wg, const float* __restrict__ bg,
    float* __restrict__ qg, float* __restrict__ ql,
    float* __restrict__ imp, float* __restrict__ gw)
{
    int b = blockIdx.x, t = threadIdx.x;
    __shared__ float cls[LAT], clsln[LAT], h1[64];
    __shared__ float mu_s, rs_s;

    const float* cp = lat_x + (size_t)(b * SEQX + NP) * LAT;
    if (t < LAT) cls[t] = cp[t];
    __syncthreads();

    if (t == 0) {
        float m = 0.f;
        for (int k = 0; k < LAT; k++) m += cls[k];
        m /= LAT;
        float v = 0.f;
        for (int k = 0; k < LAT; k++) { float d = cls[k] - m; v += d * d; }
        v /= LAT;
        float rs = rsqrtf(v + EPSF);
        mu_s = m; rs_s = rs;
        float s = bg[0];
        for (int k = 0; k < LAT; k++)
            s += ((cls[k] - m) * rs * lngg[k] + lngb[k]) * Wg[k];
        gw[b] = sigmoidf_(s);
    }
    __syncthreads();
    if (t < LAT) clsln[t] = (cls[t] - mu_s) * rs_s * lncg[t] + lncb[t];
    __syncthreads();

    {
        float s = bc1[t];
        for (int k = 0; k < LAT; k++) s += clsln[k] * Wc1[k * 64 + t];
        h1[t] = 0.5f * s * (1.f + erff(s * 0.70710678118f));
    }
    __syncthreads();
    if (t < NP) {
        float s = bc2[t];
        for (int i = 0; i < 64; i++) s += h1[i] * Wc2[i * NP + t];
        imp[b * NP + t] = sigmoidf_(s);
    }
    for (int idx = t; idx < NP * LAT; idx += 64) {
        int p = idx / LAT, j = idx % LAT;
        const float* pl = lat_x + (size_t)(b * SEQX + p) * LAT;
        float sg = bgq[j], sl = blq[j];
        for (int k = 0; k < LAT; k++) {
            float v = pl[k];
            sg += v * Wgq[k * LAT + j];
            sl += v * Wlq[k * LAT + j];
        }
        qg[(b * NP + p) * LAT + j] = sg;
        ql[(b * NP + p) * LAT + j] = sl;
    }
}

// ---------------------------------------------------------------------------
// K3: attention context (unchanged)
// ---------------------------------------------------------------------------
__global__ __launch_bounds__(256) void k_attn(const float* __restrict__ lat_x,
                                              const float* __restrict__ lat_l,
                                              const float* __restrict__ qg,
                                              const float* __restrict__ ql,
                                              float* __restrict__ ctxg,
                                              float* __restrict__ ctxl)
{
    int b = blockIdx.x, p = blockIdx.y, ty = blockIdx.z;
    const float* tok = (ty == 0) ? lat_x + (size_t)(b * SEQX + NP + 1) * LAT
                                 : lat_l + (size_t)b * SEQ * LAT;
    const float* q = ((ty == 0) ? qg : ql) + (size_t)(b * NP + p) * LAT;
    float* ctx = ((ty == 0) ? ctxg : ctxl) + (size_t)(b * NP + p) * LAT;

    int t = threadIdx.x;
    __shared__ float qs[LAT];
    __shared__ float red[128];
    __shared__ float Ms;
    __shared__ float tot[21];
    if (t < LAT) qs[t] = q[t];
    __syncthreads();

    const float scale = 0.22360679775f;   // 1/sqrt(20)
    float lg[16];
    float lmax = -1e30f;
    for (int i = 0; i < 16; i++) {
        const float* tk = tok + (size_t)(t + 256 * i) * LAT;
        float s = 0.f;
#pragma unroll
        for (int k = 0; k < LAT; k++) s += qs[k] * tk[k];
        s *= scale;
        lg[i] = s;
        lmax = fmaxf(lmax, s);
    }
    int wave = t >> 6, lane = t & 63;
    for (int off = 32; off; off >>= 1) lmax = fmaxf(lmax, __shfl_down(lmax, off, 64));
    if (lane == 0) red[wave] = lmax;
    __syncthreads();
    if (t == 0) Ms = fmaxf(fmaxf(red[0], red[1]), fmaxf(red[2], red[3]));
    __syncthreads();
    float M = Ms;

    float vals[21];
#pragma unroll
    for (int j = 0; j < 21; j++) vals[j] = 0.f;
    for (int i = 0; i < 16; i++) {
        float w = __expf(lg[i] - M);
        vals[20] += w;
        const float* tk = tok + (size_t)(t + 256 * i) * LAT;
#pragma unroll
        for (int k = 0; k < LAT; k++) vals[k] += w * tk[k];
    }
#pragma unroll
    for (int j = 0; j < 21; j++) {
        float v = vals[j];
        for (int off = 32; off; off >>= 1) v += __shfl_down(v, off, 64);
        vals[j] = v;
    }
    __syncthreads();
    if (lane == 0)
        for (int j = 0; j < 21; j++) red[wave * 21 + j] = vals[j];
    __syncthreads();
    if (t < 21) tot[t] = red[t] + red[21 + t] + red[42 + t] + red[63 + t];
    __syncthreads();
    if (t < LAT) ctx[t] = tot[t] / tot[20];
}

// ---------------------------------------------------------------------------
// K4: prompt-row outputs (unchanged)
// ---------------------------------------------------------------------------
__global__ __launch_bounds__(192) void k_prompt_out(const float* __restrict__ ctxg,
                                                    const float* __restrict__ ctxl,
                                                    const float* __restrict__ imp,
                                                    const float* __restrict__ gw,
                                                    const float* __restrict__ Wu,
                                                    const float* __restrict__ bu,
                                                    float* __restrict__ out)
{
    int b = blockIdx.x, p = blockIdx.y, t = threadIdx.x;
    __shared__ float enh[LAT];
    if (t < LAT) {
        float g = gw[b];
        size_t o = (size_t)(b * NP + p) * LAT + t;
        float e = g * ctxg[o] + (1.f - g) * ctxl[o];
        enh[t] = e * imp[b * NP + p];
    }
    __syncthreads();
    float4 acc = ((const float4*)bu)[t];
#pragma unroll
    for (int k = 0; k < LAT; k++) {
        float4 w = ((const float4*)Wu)[k * 192 + t];
        float e = enh[k];
        acc.x += e * w.x; acc.y += e * w.y; acc.z += e * w.z; acc.w += e * w.w;
    }
    ((float4*)out)[(size_t)(b * SEQX + p) * 192 + t] = acc;
}

// ---------------------------------------------------------------------------
extern "C" void kernel_launch(void* const* d_in, const int* in_sizes, int n_in,
                              void* d_out, int out_size, void* d_ws, size_t ws_size,
                              hipStream_t stream)
{
    const float* x    = (const float*)d_in[0];
    const float* loc  = (const float*)d_in[1];
    const float* Wd   = (const float*)d_in[2];
    const float* bd   = (const float*)d_in[3];
    const float* Wu   = (const float*)d_in[4];
    const float* bu   = (const float*)d_in[5];
    const float* Wgq  = (const float*)d_in[6];
    const float* bgq  = (const float*)d_in[7];
    const float* Wlq  = (const float*)d_in[8];
    const float* blq  = (const float*)d_in[9];
    const float* lncg = (const float*)d_in[10];
    const float* lncb = (const float*)d_in[11];
    const float* Wc1  = (const float*)d_in[12];
    const float* bc1  = (const float*)d_in[13];
    const float* Wc2  = (const float*)d_in[14];
    const float* bc2  = (const float*)d_in[15];
    const float* lngg = (const float*)d_in[16];
    const float* lngb = (const float*)d_in[17];
    const float* Wg   = (const float*)d_in[18];
    const float* bg   = (const float*)d_in[19];
    float* out = (float*)d_out;

    float* ws   = (float*)d_ws;
    float* lat_x = ws;                                   // NXROWS*LAT
    float* lat_l = lat_x + (size_t)NXROWS * LAT;         // NLROWS*LAT (contiguous)
    float* qg    = lat_l + (size_t)NLROWS * LAT;
    float* ql    = qg + NB * NP * LAT;
    float* ctxg  = ql + NB * NP * LAT;
    float* ctxl  = ctxg + NB * NP * LAT;
    float* impw  = ctxl + NB * NP * LAT;
    float* gww   = impw + NB * NP;
    unsigned short* wfrag = (unsigned short*)(gww + NB); // 48 KB frag image (16B-aligned)

    k_wfrag<<<12, 256, 0, stream>>>(Wd, wfrag);
    k_down<<<(NROWS + 63) / 64, 256, 0, stream>>>(x, loc, wfrag, bd, lat_x);
    k_up<<<(NXROWS + 63) / 64, 192, 0, stream>>>(lat_x, Wu, bu, out);
    k_small<<<NB, 64, 0, stream>>>(lat_x, Wgq, bgq, Wlq, blq, lncg, lncb,
                                   Wc1, bc1, Wc2, bc2, lngg, lngb, Wg, bg,
                                   qg, ql, impw, gww);
    k_attn<<<dim3(NB, NP, 2), 256, 0, stream>>>(lat_x, lat_l, qg, ql, ctxg, ctxl);
    k_prompt_out<<<dim3(NB, NP), 192, 0, stream>>>(ctxg, ctxl, impw, gww, Wu, bu, out);
}